// Round 10
// baseline (82.979 us; speedup 1.0000x reference)
//
#include <hip/hip_runtime.h>
#include <hip/hip_bf16.h>

#define Bv 8
#define Nv 512
#define Dv 1024
#define Ev 8
#define Hv 8
#define HDv 128
#define EPSv 1e-5f

typedef __attribute__((ext_vector_type(8))) short short8;
typedef __attribute__((ext_vector_type(4))) float f32x4;

__device__ __forceinline__ unsigned short f2b(float f) {
    __hip_bfloat16 h = __float2bfloat16(f);
    return *reinterpret_cast<unsigned short*>(&h);
}
__device__ __forceinline__ float bf2f(unsigned int u) {
    union { unsigned int i; float f; } v; v.i = u << 16; return v.f;
}

// async global->LDS, 16 bytes per lane; LDS dest must be linear (base + lane*16)
__device__ __forceinline__ void gld16(const void* g, void* l) {
    __builtin_amdgcn_global_load_lds(
        (const __attribute__((address_space(1))) void*)(uintptr_t)(g),
        (__attribute__((address_space(3))) void*)(uintptr_t)(l), 16, 0, 0);
}

// ---------------- preprocessing: only the small casts -----------------------
//   blocks [0,128):    cast x->bf16 + column partial sums
//   blocks [128,256):  cast in_w -> bf16
//   blocks [256,384):  cast out_w -> bf16
__global__ __launch_bounds__(256) void k_preA(const float* __restrict__ x,
                                              const float* __restrict__ w1,
                                              const float* __restrict__ w2,
                                              unsigned short* __restrict__ xb,
                                              float* __restrict__ part_x,
                                              unsigned short* __restrict__ w1b,
                                              unsigned short* __restrict__ w2b) {
    int bid = blockIdx.x;
    int t = threadIdx.x;
    if (bid < 128) {
        int b = bid >> 4, c = bid & 15;
        const float* px = x + ((size_t)b * Nv + c * 32) * Dv + t * 4;
        unsigned short* qx = xb + ((size_t)b * Nv + c * 32) * Dv + t * 4;
        float4 s4 = make_float4(0.f, 0.f, 0.f, 0.f);
        #pragma unroll 8
        for (int r = 0; r < 32; ++r) {
            float4 v = *(const float4*)(px + (size_t)r * Dv);
            s4.x += v.x; s4.y += v.y; s4.z += v.z; s4.w += v.w;
            uint2 pk;
            pk.x = (unsigned)f2b(v.x) | ((unsigned)f2b(v.y) << 16);
            pk.y = (unsigned)f2b(v.z) | ((unsigned)f2b(v.w) << 16);
            *(uint2*)(qx + (size_t)r * Dv) = pk;
        }
        *(float4*)(part_x + ((size_t)(b * 16 + c)) * Dv + t * 4) = s4;
        return;
    }
    const float* src; unsigned short* dst; int base;
    if (bid < 256) { src = w1; dst = w1b; base = (bid - 128) * 8192; }
    else           { src = w2; dst = w2b; base = (bid - 256) * 8192; }
    #pragma unroll
    for (int i = 0; i < 8; ++i) {
        float4 a = *(const float4*)(src + base + i * 1024 + t * 4);
        uint2 p;
        p.x = (unsigned)f2b(a.x) | ((unsigned)f2b(a.y) << 16);
        p.y = (unsigned)f2b(a.z) | ((unsigned)f2b(a.w) << 16);
        *(uint2*)(dst + base + i * 1024 + t * 4) = p;
    }
}

// ---------------- bf16 MFMA GEMM, depth-2 pipelined (3 LDS buffers) ---------
// MODE 0: C[m,n] = A[m,:].W[n,:] + bias[n], f32 out, normal layout
// MODE 2: bf16 out TRANSPOSED to Cv[b][n(d)][tok] (shape [Bv][Dv][Nv]) plus
//         per-(b,d) partial LN sums part[(b*Dv+d)*4 + m_chunk] = (sum, sumsq);
//         also reduces part_x -> xmean (overlapped with staging prologue)
template <int MODE>
__global__ __launch_bounds__(256) void k_gemm(
    const unsigned short* __restrict__ A,   // [M][K] bf16
    const unsigned short* __restrict__ W,   // [Nn][K] bf16
    const float* __restrict__ bias,         // [Nn] f32
    void* __restrict__ Cv,
    float2* __restrict__ part,
    const float* __restrict__ part_x,
    float* __restrict__ xmean,
    int M, int Nn, int K) {
    __shared__ __align__(16) unsigned short sA[3][128 * 64];
    __shared__ __align__(16) unsigned short sB[3][128 * 64];
    const int t = threadIdx.x;
    const int bn = blockIdx.x * 128;
    const int bm = blockIdx.y * 128;
    const int lane = t & 63;
    const int w = t >> 6, wm = w >> 1, wn = w & 1;
    const int fr = lane & 15, fq = lane >> 4;
    const int NT = K >> 6;
    f32x4 acc[4][4] = {};

#define STAGE(s, k0)                                                        \
    {                                                                       \
        _Pragma("unroll")                                                   \
        for (int i_ = 0; i_ < 4; ++i_) {                                    \
            int c_ = t + i_ * 256;                                          \
            int row_ = c_ >> 3, col_ = c_ & 7;                              \
            int cs_ = col_ ^ (row_ & 7);                                    \
            gld16(A + (size_t)(bm + row_) * K + (k0) + cs_ * 8, &sA[s][c_ * 8]); \
            gld16(W + (size_t)(bn + row_) * K + (k0) + cs_ * 8, &sB[s][c_ * 8]); \
        }                                                                   \
    }

    STAGE(0, 0);
    STAGE(1, 64);
    if (MODE == 2) {
        // xmean reduce: 256 blocks x 32 outputs, overlapped with async staging
        int blk = blockIdx.y * 8 + blockIdx.x;      // 0..255
        int o = blk * 32 + (t >> 3);                // output idx over 8192
        int c2 = t & 7;
        int b2 = o >> 10, d2 = o & 1023;
        float S = part_x[((size_t)(b2 * 16 + c2)) * Dv + d2]
                + part_x[((size_t)(b2 * 16 + c2 + 8)) * Dv + d2];
        S += __shfl_xor(S, 1); S += __shfl_xor(S, 2); S += __shfl_xor(S, 4);
        if (c2 == 0) xmean[o] = S * (1.f / Nv);
    }
    for (int it = 0; it < NT; ++it) {
        if (it + 2 < NT) {
            STAGE((it + 2) % 3, (it + 2) * 64);
            asm volatile("s_waitcnt vmcnt(16)" ::: "memory");
        } else if (it + 1 < NT) {
            asm volatile("s_waitcnt vmcnt(8)" ::: "memory");
        } else {
            asm volatile("s_waitcnt vmcnt(0)" ::: "memory");
        }
        __builtin_amdgcn_s_barrier();
        const unsigned short* pA = sA[it % 3];
        const unsigned short* pB = sB[it % 3];
        #pragma unroll
        for (int kk = 0; kk < 2; ++kk) {
            short8 af[4], bv[4];
            #pragma unroll
            for (int i = 0; i < 4; ++i)
                af[i] = *(const short8*)&pA[(wm * 64 + i * 16 + fr) * 64 + (((kk << 2) + fq) ^ (fr & 7)) * 8];
            #pragma unroll
            for (int j = 0; j < 4; ++j)
                bv[j] = *(const short8*)&pB[(wn * 64 + j * 16 + fr) * 64 + (((kk << 2) + fq) ^ (fr & 7)) * 8];
            #pragma unroll
            for (int i = 0; i < 4; ++i)
                #pragma unroll
                for (int j = 0; j < 4; ++j)
                    acc[i][j] = __builtin_amdgcn_mfma_f32_16x16x32_bf16(af[i], bv[j], acc[i][j], 0, 0, 0);
        }
        __builtin_amdgcn_s_barrier();
    }
#undef STAGE
    if (MODE == 0) {
        #pragma unroll
        for (int j = 0; j < 4; ++j) {
            const int n = bn + wn * 64 + j * 16 + fr;
            const float bj = bias[n];
            #pragma unroll
            for (int i = 0; i < 4; ++i) {
                const int m0 = bm + wm * 64 + i * 16 + fq * 4;
                #pragma unroll
                for (int r = 0; r < 4; ++r)
                    ((float*)Cv)[(size_t)(m0 + r) * Nn + n] = acc[i][j][r] + bj;
            }
        }
    } else {
        // ---- transposed bf16 tile via LDS (K-loop LDS is dead now) + stats ----
        unsigned short* sc = &sA[0][0];        // [128 d][136 tok] ushort = 34 KB
        float2* red = (float2*)&sB[0][0];      // [128 d][8] partial (s,q) = 8 KB
        const int bB   = bm >> 9;              // batch
        const int tok0 = bm & 511;             // token offset within batch
        const int chunk = (bm >> 7) & 3;       // which 128-token chunk
        #pragma unroll
        for (int j = 0; j < 4; ++j) {
            const int col = wn * 64 + j * 16 + fr;       // local d
            const float bj = bias[bn + col];
            float s = 0.f, q = 0.f;
            #pragma unroll
            for (int i = 0; i < 4; ++i) {
                const int row0 = wm * 64 + i * 16 + fq * 4;  // local token
                #pragma unroll
                for (int r = 0; r < 4; r += 2) {
                    float v0 = acc[i][j][r] + bj;
                    float v1 = acc[i][j][r + 1] + bj;
                    s += v0 + v1;
                    q = fmaf(v0, v0, fmaf(v1, v1, q));
                    unsigned int pk = (unsigned int)f2b(v0) | ((unsigned int)f2b(v1) << 16);
                    *(unsigned int*)&sc[col * 136 + row0 + r] = pk;
                }
            }
            red[col * 8 + wm * 4 + fq] = make_float2(s, q);
        }
        __syncthreads();
        if (t < 128) {
            float S = 0.f, Q = 0.f;
            #pragma unroll
            for (int k = 0; k < 8; ++k) { float2 v = red[t * 8 + k]; S += v.x; Q += v.y; }
            part[((size_t)bB * Dv + bn + t) * 4 + chunk] = make_float2(S, Q);
        }
        unsigned short* dst = (unsigned short*)Cv;
        #pragma unroll
        for (int k = 0; k < 8; ++k) {
            const int c = t + k * 256;
            const int dl = c >> 4, tk = c & 15;
            uint4 v = *(const uint4*)&sc[dl * 136 + tk * 8];
            *(uint4*)&dst[((size_t)bB * Dv + bn + dl) * Nv + tok0 + tk * 8] = v;
        }
    }
}

// ---------------- mixer GEMM: two-expert unnormalized-exp accumulation -----
// BM=64 (grid 8x64), single-buffered A LDS (~50 KB total -> 2 blocks/CU),
// 2-deep register prefetch of raw f32 weight (raA/raB ping-pong).
//   acc_e[m,d] = sum_n exp(w_e[m,n]) * xp[d,n];  s_e[m] = sum_n exp(w_e[m,n])
//   out = rstd_d*((tw0/s0[m])*acc0 + (tw1/s1[m])*acc1 - mu_d) + blended bias
// No max-subtraction: |w| <= 1/sqrt(512) so exp in [0.957, 1.045].
__global__ __launch_bounds__(256) void k_mixg(
    const float* __restrict__ weight,         // [E][H][512][512] f32 raw
    const unsigned short* __restrict__ xpT,   // [8][1024][512] bf16 (raw xp, transposed)
    const float* __restrict__ bias,           // [E][H][512] f32
    const float* __restrict__ xmean,          // [8][1024] f32
    const float* __restrict__ router_w,       // [E][1024] f32
    const float2* __restrict__ part,          // [(b*Dv+d)*4 + chunk] (sum,sumsq)
    unsigned short* __restrict__ y,           // [8][512][1024] bf16
    float* __restrict__ aux_out) {
    __shared__ __align__(16) unsigned short sA0[64 * 64];   // 8 KB, single buffer
    __shared__ __align__(16) unsigned short sA1[64 * 64];   // 8 KB
    __shared__ __align__(16) unsigned short sB[2][128 * 64]; // 32 KB
    __shared__ float rowc0[64], rowc1[64];
    __shared__ float probs[Bv][Ev];
    __shared__ float twsh[Bv][2];
    __shared__ int   tsel[Bv][2];
    __shared__ int   top1s[Bv];
    const int t = threadIdx.x;
    const int bm = blockIdx.x * 64;   // m tile (8)
    const int bh = blockIdx.y;        // 64
    const int b = bh >> 3, h = bh & 7;

    // ---- redundant per-block router: 64 dots (b,e) x 4 lanes each ----
    {
        int pid = t >> 2, l = t & 3;
        int rb = pid >> 3, re = pid & 7;
        const float4* xm = (const float4*)(xmean + rb * Dv);
        const float4* rw = (const float4*)(router_w + re * Dv);
        float s = 0.f;
        #pragma unroll
        for (int j = 0; j < 64; ++j) {
            float4 aa = xm[l + j * 4], ww = rw[l + j * 4];
            s = fmaf(aa.x, ww.x, s); s = fmaf(aa.y, ww.y, s);
            s = fmaf(aa.z, ww.z, s); s = fmaf(aa.w, ww.w, s);
        }
        s += __shfl_xor(s, 1); s += __shfl_xor(s, 2);
        if (l == 0) probs[rb][re] = s;
    }
    __syncthreads();
    if (t < Bv) {
        int bb = t;
        float mx = -1e30f;
        for (int e2 = 0; e2 < Ev; ++e2) mx = fmaxf(mx, probs[bb][e2]);
        float sum = 0.f;
        for (int e2 = 0; e2 < Ev; ++e2) { float v = __expf(probs[bb][e2] - mx); probs[bb][e2] = v; sum += v; }
        float inv = 1.f / sum;
        for (int e2 = 0; e2 < Ev; ++e2) probs[bb][e2] *= inv;
        int i0 = 0; float p0 = probs[bb][0];
        for (int e2 = 1; e2 < Ev; ++e2) if (probs[bb][e2] > p0) { p0 = probs[bb][e2]; i0 = e2; }
        int i1 = -1; float p1 = -1.f;
        for (int e2 = 0; e2 < Ev; ++e2) if (e2 != i0 && probs[bb][e2] > p1) { p1 = probs[bb][e2]; i1 = e2; }
        float s2 = p0 + p1;
        tsel[bb][0] = i0; tsel[bb][1] = i1;
        twsh[bb][0] = p0 / s2; twsh[bb][1] = p1 / s2;
        top1s[bb] = i0;
    }
    __syncthreads();
    if (blockIdx.x == 0 && bh == 0 && t == 0) {
        float aux = 0.f;
        for (int e2 = 0; e2 < Ev; ++e2) {
            float pm = 0.f, mm = 0.f;
            for (int bb = 0; bb < Bv; ++bb) { pm += probs[bb][e2]; mm += (top1s[bb] == e2) ? 1.f : 0.f; }
            aux += (pm / Bv) * (mm / Bv);
        }
        *aux_out = aux * Ev;
    }
    const int e0 = tsel[b][0], e1 = tsel[b][1];
    const float tw0 = twsh[b][0], tw1 = twsh[b][1];

    const int lane = t & 63;
    const int w = t >> 6, wm = w >> 1, wn = w & 1;
    const int fr = lane & 15, fq = lane >> 4;

    // ---- LN stats from gemm1 partials ----
    float rstd_j[4], nmr_j[4];
    #pragma unroll
    for (int j = 0; j < 4; ++j) {
        const int dg = h * HDv + wn * 64 + j * 16 + fr;
        const float2* pp = part + ((size_t)b * Dv + dg) * 4;
        float S = 0.f, Q = 0.f;
        #pragma unroll
        for (int cc = 0; cc < 4; ++cc) { float2 v = pp[cc]; S += v.x; Q += v.y; }
        float mu = S * (1.f / Nv);
        float var = Q * (1.f / Nv) - mu * mu;
        float rs = rsqrtf(var + EPSv);
        rstd_j[j] = rs; nmr_j[j] = -mu * rs;
    }

    const float* W0 = weight + (size_t)(e0 * Hv + h) * Nv * Nv;
    const float* W1 = weight + (size_t)(e1 * Hv + h) * Nv * Nv;
    const unsigned short* Bb = xpT + ((size_t)b * Dv + h * HDv) * Nv;

    f32x4 acc0[2][4] = {}, acc1[2][4] = {};
    float4 raA0[2][2], raA1[2][2], raB0[2][2], raB1[2][2];
    float s0p[2] = {0.f, 0.f}, s1p[2] = {0.f, 0.f};

#define BSTAGE(s, k0)                                                       \
    {                                                                       \
        _Pragma("unroll")                                                   \
        for (int i_ = 0; i_ < 4; ++i_) {                                    \
            int c_ = t + i_ * 256;                                          \
            int row_ = c_ >> 3, col_ = c_ & 7;                              \
            int cs_ = col_ ^ (row_ & 7);                                    \
            gld16(Bb + (size_t)row_ * Nv + (k0) + cs_ * 8, &sB[s][c_ * 8]); \
        }                                                                   \
    }
#define ALOADG(RA0, RA1, k0)                                                \
    {                                                                       \
        _Pragma("unroll")                                                   \
        for (int i_ = 0; i_ < 2; ++i_) {                                    \
            int c_ = t + i_ * 256;                                          \
            int row_ = c_ >> 3, col_ = c_ & 7;                              \
            int cs_ = col_ ^ (row_ & 7);                                    \
            size_t off_ = (size_t)(bm + row_) * Nv + (k0) + cs_ * 8;        \
            RA0[i_][0] = *(const float4*)&W0[off_];                         \
            RA0[i_][1] = *(const float4*)&W0[off_ + 4];                     \
            RA1[i_][0] = *(const float4*)&W1[off_];                         \
            RA1[i_][1] = *(const float4*)&W1[off_ + 4];                     \
        }                                                                   \
    }
#define BLEND(RA0, RA1)                                                     \
    {                                                                       \
        _Pragma("unroll")                                                   \
        for (int i_ = 0; i_ < 2; ++i_) {                                    \
            int c_ = t + i_ * 256;                                          \
            float e0v[8], e1v[8];                                           \
            const float4 a0_ = RA0[i_][0], a1_ = RA0[i_][1];                \
            const float4 b0_ = RA1[i_][0], b1_ = RA1[i_][1];                \
            e0v[0] = __expf(a0_.x); e0v[1] = __expf(a0_.y);                 \
            e0v[2] = __expf(a0_.z); e0v[3] = __expf(a0_.w);                 \
            e0v[4] = __expf(a1_.x); e0v[5] = __expf(a1_.y);                 \
            e0v[6] = __expf(a1_.z); e0v[7] = __expf(a1_.w);                 \
            e1v[0] = __expf(b0_.x); e1v[1] = __expf(b0_.y);                 \
            e1v[2] = __expf(b0_.z); e1v[3] = __expf(b0_.w);                 \
            e1v[4] = __expf(b1_.x); e1v[5] = __expf(b1_.y);                 \
            e1v[6] = __expf(b1_.z); e1v[7] = __expf(b1_.w);                 \
            s0p[i_] += ((e0v[0] + e0v[1]) + (e0v[2] + e0v[3]))              \
                     + ((e0v[4] + e0v[5]) + (e0v[6] + e0v[7]));             \
            s1p[i_] += ((e1v[0] + e1v[1]) + (e1v[2] + e1v[3]))              \
                     + ((e1v[4] + e1v[5]) + (e1v[6] + e1v[7]));             \
            uint4 p0_, p1_;                                                 \
            p0_.x = (unsigned)f2b(e0v[0]) | ((unsigned)f2b(e0v[1]) << 16);  \
            p0_.y = (unsigned)f2b(e0v[2]) | ((unsigned)f2b(e0v[3]) << 16);  \
            p0_.z = (unsigned)f2b(e0v[4]) | ((unsigned)f2b(e0v[5]) << 16);  \
            p0_.w = (unsigned)f2b(e0v[6]) | ((unsigned)f2b(e0v[7]) << 16);  \
            p1_.x = (unsigned)f2b(e1v[0]) | ((unsigned)f2b(e1v[1]) << 16);  \
            p1_.y = (unsigned)f2b(e1v[2]) | ((unsigned)f2b(e1v[3]) << 16);  \
            p1_.z = (unsigned)f2b(e1v[4]) | ((unsigned)f2b(e1v[5]) << 16);  \
            p1_.w = (unsigned)f2b(e1v[6]) | ((unsigned)f2b(e1v[7]) << 16);  \
            *(uint4*)&sA0[c_ * 8] = p0_;                                    \
            *(uint4*)&sA1[c_ * 8] = p1_;                                    \
        }                                                                   \
    }
#define MFMAPH(sbuf)                                                        \
    {                                                                       \
        const unsigned short* pB = sB[sbuf];                                \
        _Pragma("unroll")                                                   \
        for (int kk = 0; kk < 2; ++kk) {                                    \
            short8 bv[4];                                                   \
            _Pragma("unroll")                                               \
            for (int j = 0; j < 4; ++j)                                     \
                bv[j] = *(const short8*)&pB[(wn * 64 + j * 16 + fr) * 64 + (((kk << 2) + fq) ^ (fr & 7)) * 8]; \
            _Pragma("unroll")                                               \
            for (int i = 0; i < 2; ++i) {                                   \
                const int aoff = (wm * 32 + i * 16 + fr) * 64 + (((kk << 2) + fq) ^ (fr & 7)) * 8; \
                short8 af0 = *(const short8*)&sA0[aoff];                    \
                short8 af1 = *(const short8*)&sA1[aoff];                    \
                _Pragma("unroll")                                           \
                for (int j = 0; j < 4; ++j)                                 \
                    acc0[i][j] = __builtin_amdgcn_mfma_f32_16x16x32_bf16(af0, bv[j], acc0[i][j], 0, 0, 0); \
                _Pragma("unroll")                                           \
                for (int j = 0; j < 4; ++j)                                 \
                    acc1[i][j] = __builtin_amdgcn_mfma_f32_16x16x32_bf16(af1, bv[j], acc1[i][j], 0, 0, 0); \
            }                                                               \
        }                                                                   \
    }
// vmcnt at iter it drains ALOAD(it)[8] + BSTAGE(it)[4]; leaves
// ALOAD(it+1)[8] + BSTAGE(it+1)[4] = 12 in flight (0 at the last iter).
#define FITER(it, RA0, RA1)                                                 \
    {                                                                       \
        if ((it) + 1 < 8) BSTAGE(((it) + 1) & 1, ((it) + 1) * 64);          \
        if ((it) < 7) { asm volatile("s_waitcnt vmcnt(12)" ::: "memory"); } \
        else          { asm volatile("s_waitcnt vmcnt(0)" ::: "memory"); }  \
        BLEND(RA0, RA1);                                                    \
        if ((it) + 2 < 8) ALOADG(RA0, RA1, ((it) + 2) * 64);                \
        asm volatile("s_waitcnt lgkmcnt(0)" ::: "memory");                  \
        __builtin_amdgcn_s_barrier();                                       \
        MFMAPH((it) & 1);                                                   \
        __builtin_amdgcn_s_barrier();                                       \
    }

    BSTAGE(0, 0);
    ALOADG(raA0, raA1, 0);
    ALOADG(raB0, raB1, 64);
    FITER(0, raA0, raA1);
    FITER(1, raB0, raB1);
    FITER(2, raA0, raA1);
    FITER(3, raB0, raB1);
    FITER(4, raA0, raA1);
    FITER(5, raB0, raB1);
    FITER(6, raA0, raA1);
    FITER(7, raB0, raB1);
#undef BSTAGE
#undef ALOADG
#undef BLEND
#undef MFMAPH
#undef FITER

    // ---- finalize row sums: reduce over the 8 lanes sharing each row ----
    #pragma unroll
    for (int i = 0; i < 2; ++i) {
        #pragma unroll
        for (int off = 1; off < 8; off <<= 1) {
            s0p[i] += __shfl_xor(s0p[i], off);
            s1p[i] += __shfl_xor(s1p[i], off);
        }
        int row = (t >> 3) + i * 32;   // == (t + i*256) >> 3
        if ((t & 7) == 0) {
            rowc0[row] = tw0 / s0p[i];
            rowc1[row] = tw1 / s1p[i];
        }
    }
    __syncthreads();

    // ---- epilogue: y = rstd_d*(c0*acc0 + c1*acc1 - mu_d) + blended bias ----
    #pragma unroll
    for (int i = 0; i < 2; ++i) {
        #pragma unroll
        for (int r = 0; r < 4; ++r) {
            const int ml = wm * 32 + i * 16 + fq * 4 + r;
            const int m = bm + ml;
            const float c0m = rowc0[ml], c1m = rowc1[ml];
            const float br = tw0 * bias[(size_t)(e0 * Hv + h) * Nv + m]
                           + tw1 * bias[(size_t)(e1 * Hv + h) * Nv + m];
            #pragma unroll
            for (int j = 0; j < 4; ++j) {
                const int d = wn * 64 + j * 16 + fr;
                float vb = c0m * acc0[i][j][r] + c1m * acc1[i][j][r];
                float v = fmaf(vb, rstd_j[j], nmr_j[j] + br);
                y[((size_t)b * Nv + m) * Dv + h * HDv + d] = f2b(v);
            }
        }
    }
}

extern "C" void kernel_launch(void* const* d_in, const int* in_sizes, int n_in,
                              void* d_out, int out_size, void* d_ws, size_t ws_size,
                              hipStream_t stream) {
    const float* x        = (const float*)d_in[0];
    const float* weight   = (const float*)d_in[1];
    const float* bias     = (const float*)d_in[2];
    const float* router_w = (const float*)d_in[3];
    const float* in_w     = (const float*)d_in[4];
    const float* in_b     = (const float*)d_in[5];
    const float* out_w    = (const float*)d_in[6];
    const float* out_b    = (const float*)d_in[7];
    float* out = (float*)d_out;

    if (ws_size < ((size_t)63 << 20)) return;

    char* wsb = (char*)d_ws;
    float*  xmean  = (float*)(wsb);                                  // 32 KB
    float2* part   = (float2*)(wsb + (64 << 10));                    // 256 KB
    float*  part_x = (float*)(wsb + (512 << 10));                    // 512 KB
    unsigned short* in_wb  = (unsigned short*)(wsb + ((size_t)2 << 20));   // 2 MB
    unsigned short* out_wb = (unsigned short*)(wsb + ((size_t)4 << 20));   // 2 MB
    unsigned short* xb     = (unsigned short*)(wsb + ((size_t)8 << 20));   // 8 MB (later y)
    unsigned short* xpT    = (unsigned short*)(wsb + ((size_t)16 << 20));  // 8 MB
    unsigned short* y = xb;  // xb dead after gemm1

    k_preA<<<384, 256, 0, stream>>>(x, in_w, out_w, xb, part_x, in_wb, out_wb);
    k_gemm<2><<<dim3(8, 32), 256, 0, stream>>>(xb, in_wb, in_b, xpT, part, part_x, xmean,
                                               Bv * Nv, Dv, Dv);
    k_mixg<<<dim3(8, 64), 256, 0, stream>>>(weight, xpT, bias, xmean, router_w, part, y,
                                            out + (size_t)Bv * Nv * Dv);
    k_gemm<0><<<dim3(8, 32), 256, 0, stream>>>(y, out_wb, out_b, out, nullptr, nullptr, nullptr,
                                               Bv * Nv, Dv, Dv);
}